// Round 1
// baseline (536.327 us; speedup 1.0000x reference)
//
#include <hip/hip_runtime.h>
#include <hip/hip_bf16.h>

// GraphSAGE 2-layer: out = sage2(relu(sage1(x)))
// sage(feat) = mean_agg(feat) @ Wl^T + feat @ Wr^T + b
// N=100000, E=625000, D=128 (derived from in_sizes at runtime).

#define D 128
#define SCAN_BLK 1024

// ---------------- CSR construction ----------------

__global__ void count_deg(const int* __restrict__ ei, int* __restrict__ deg, int E) {
    int e = blockIdx.x * 256 + threadIdx.x;
    if (e < E) atomicAdd(&deg[ei[E + e]], 1);   // dst row
}

__global__ __launch_bounds__(SCAN_BLK) void scan_local(
        const int* __restrict__ deg, int* __restrict__ rowptr,
        int* __restrict__ partials, int n) {
    __shared__ int sdata[SCAN_BLK];
    int tid = threadIdx.x;
    int i = blockIdx.x * SCAN_BLK + tid;
    int v = (i < n) ? deg[i] : 0;
    sdata[tid] = v;
    __syncthreads();
    #pragma unroll
    for (int off = 1; off < SCAN_BLK; off <<= 1) {
        int t = (tid >= off) ? sdata[tid - off] : 0;
        __syncthreads();
        sdata[tid] += t;
        __syncthreads();
    }
    if (i < n) rowptr[i] = sdata[tid] - v;              // local exclusive
    if (tid == SCAN_BLK - 1) partials[blockIdx.x] = sdata[SCAN_BLK - 1];
}

__global__ __launch_bounds__(SCAN_BLK) void scan_partials(
        const int* __restrict__ partials, int* __restrict__ bases,
        int* __restrict__ rowptr, int nblocks, int n) {
    __shared__ int sdata[SCAN_BLK];
    int tid = threadIdx.x;
    int v = (tid < nblocks) ? partials[tid] : 0;
    sdata[tid] = v;
    __syncthreads();
    #pragma unroll
    for (int off = 1; off < SCAN_BLK; off <<= 1) {
        int t = (tid >= off) ? sdata[tid - off] : 0;
        __syncthreads();
        sdata[tid] += t;
        __syncthreads();
    }
    if (tid < nblocks) bases[tid] = sdata[tid] - v;
    if (tid == SCAN_BLK - 1) rowptr[n] = sdata[SCAN_BLK - 1];  // total = E
}

__global__ void add_bases(int* __restrict__ rowptr, const int* __restrict__ bases, int n) {
    int i = blockIdx.x * 256 + threadIdx.x;
    if (i < n) rowptr[i] += bases[i >> 10];
}

__global__ void fill_csr(const int* __restrict__ ei, int* __restrict__ cursor,
                         const int* __restrict__ rowptr, int* __restrict__ csr, int E) {
    int e = blockIdx.x * 256 + threadIdx.x;
    if (e < E) {
        int s = ei[e];          // src
        int d = ei[E + e];      // dst
        int pos = atomicAdd(&cursor[d], 1);
        csr[rowptr[d] + pos] = s;
    }
}

// ---------------- mean aggregation: one wave per node ----------------

__global__ __launch_bounds__(256) void agg_mean(
        const float* __restrict__ feat, const int* __restrict__ rowptr,
        const int* __restrict__ csr, float* __restrict__ aggout, int n) {
    int node = (blockIdx.x * 256 + threadIdx.x) >> 6;
    int lane = threadIdx.x & 63;
    if (node >= n) return;
    int beg = rowptr[node], end = rowptr[node + 1];
    const float2* f2 = (const float2*)feat;
    float2 acc = make_float2(0.f, 0.f);
    for (int e = beg; e < end; ++e) {
        int s = csr[e];
        float2 v = f2[s * 64 + lane];
        acc.x += v.x;
        acc.y += v.y;
    }
    float inv = (end > beg) ? 1.0f / (float)(end - beg) : 0.0f;
    float2* o2 = (float2*)aggout;
    o2[node * 64 + lane] = make_float2(acc.x * inv, acc.y * inv);
}

// ---------------- fused dual GEMM: out = agg@Wl^T + feat@Wr^T + b ----------------
// Treated as [N,256] @ [256,128]: K chunks 0..3 from (agg,Wl), 4..7 from (feat,Wr).

#define BM 64
#define BN 128
#define BK 32

template <bool RELU>
__global__ __launch_bounds__(256) void sage_gemm(
        const float* __restrict__ agg, const float* __restrict__ feat,
        const float* __restrict__ Wl, const float* __restrict__ Wr,
        const float* __restrict__ bias, float* __restrict__ outp, int n) {
    __shared__ float As[BK][BM + 1];   // [k][m], +1 pad
    __shared__ float Bs[BK][BN + 1];   // [k][o], +1 pad
    int tid = threadIdx.x;
    int m0 = blockIdx.x * BM;
    int tx = tid & 15;    // output groups: o = tx + 16j
    int ty = tid >> 4;    // node groups:   m = ty + 16i

    float acc[4][8];
    #pragma unroll
    for (int i = 0; i < 4; ++i)
        #pragma unroll
        for (int j = 0; j < 8; ++j) acc[i][j] = 0.f;

    for (int kc = 0; kc < 8; ++kc) {
        const float* Asrc = (kc < 4) ? agg : feat;
        const float* Bsrc = (kc < 4) ? Wl : Wr;
        int kbase = (kc & 3) * BK;

        // A tile: 64 rows x 32 k  (2048 floats, 2 float4/thread)
        {
            int kq = tid & 7;       // k = kq*4
            int ml = tid >> 3;      // 0..31
            #pragma unroll
            for (int rep = 0; rep < 2; ++rep) {
                int row = ml + rep * 32;
                int gm = m0 + row;
                float4 v = make_float4(0.f, 0.f, 0.f, 0.f);
                if (gm < n) v = *(const float4*)&Asrc[gm * D + kbase + kq * 4];
                As[kq * 4 + 0][row] = v.x;
                As[kq * 4 + 1][row] = v.y;
                As[kq * 4 + 2][row] = v.z;
                As[kq * 4 + 3][row] = v.w;
            }
        }
        // B tile: 128 outs x 32 k (4096 floats, 4 float4/thread)
        {
            int kq = tid & 7;
            int ol = tid >> 3;      // 0..31
            #pragma unroll
            for (int rep = 0; rep < 4; ++rep) {
                int o = ol + rep * 32;
                float4 v = *(const float4*)&Bsrc[o * D + kbase + kq * 4];
                Bs[kq * 4 + 0][o] = v.x;
                Bs[kq * 4 + 1][o] = v.y;
                Bs[kq * 4 + 2][o] = v.z;
                Bs[kq * 4 + 3][o] = v.w;
            }
        }
        __syncthreads();

        #pragma unroll
        for (int kk = 0; kk < BK; ++kk) {
            float a[4], b[8];
            #pragma unroll
            for (int i = 0; i < 4; ++i) a[i] = As[kk][ty + i * 16];
            #pragma unroll
            for (int j = 0; j < 8; ++j) b[j] = Bs[kk][tx + j * 16];
            #pragma unroll
            for (int i = 0; i < 4; ++i)
                #pragma unroll
                for (int j = 0; j < 8; ++j)
                    acc[i][j] += a[i] * b[j];
        }
        __syncthreads();
    }

    #pragma unroll
    for (int i = 0; i < 4; ++i) {
        int gm = m0 + ty + i * 16;
        if (gm >= n) continue;
        #pragma unroll
        for (int j = 0; j < 8; ++j) {
            int o = tx + j * 16;
            float v = acc[i][j] + bias[o];
            if (RELU) v = fmaxf(v, 0.f);
            outp[gm * D + o] = v;
        }
    }
}

// ---------------- launch ----------------

extern "C" void kernel_launch(void* const* d_in, const int* in_sizes, int n_in,
                              void* d_out, int out_size, void* d_ws, size_t ws_size,
                              hipStream_t stream) {
    const float* x    = (const float*)d_in[0];
    const int*   ei   = (const int*)d_in[1];
    const float* W1l  = (const float*)d_in[2];
    const float* b1   = (const float*)d_in[3];
    const float* W1r  = (const float*)d_in[4];
    const float* W2l  = (const float*)d_in[5];
    const float* b2   = (const float*)d_in[6];
    const float* W2r  = (const float*)d_in[7];
    float* out = (float*)d_out;

    const int N = in_sizes[0] / D;
    const int E = in_sizes[1] / 2;

    // workspace layout
    float* agg    = (float*)d_ws;                     // N*D f32
    int*   deg    = (int*)(agg + (size_t)N * D);      // N
    int*   rowptr = deg + N;                          // N+1
    int*   cursor = rowptr + N + 1;                   // N
    int*   csr    = cursor + N;                       // E
    int*   parts  = csr + E;                          // 1024
    int*   bases  = parts + SCAN_BLK;                 // 1024

    const int nchunks = (N + SCAN_BLK - 1) / SCAN_BLK;
    const int eblk = (E + 255) / 256;
    const int nblk = (N + 255) / 256;

    hipMemsetAsync(deg, 0, (size_t)N * sizeof(int), stream);
    hipMemsetAsync(cursor, 0, (size_t)N * sizeof(int), stream);

    // Build CSR (dst -> list of src), shared by both layers
    count_deg<<<eblk, 256, 0, stream>>>(ei, deg, E);
    scan_local<<<nchunks, SCAN_BLK, 0, stream>>>(deg, rowptr, parts, N);
    scan_partials<<<1, SCAN_BLK, 0, stream>>>(parts, bases, rowptr, nchunks, N);
    add_bases<<<nblk, 256, 0, stream>>>(rowptr, bases, N);
    fill_csr<<<eblk, 256, 0, stream>>>(ei, cursor, rowptr, csr, E);

    const int aggblk = (N * 64 + 255) / 256;   // one wave (64 lanes) per node
    const int gemmblk = (N + BM - 1) / BM;

    // Layer 1: h = relu(sage(x))  -> store h in d_out
    agg_mean<<<aggblk, 256, 0, stream>>>(x, rowptr, csr, agg, N);
    sage_gemm<true><<<gemmblk, 256, 0, stream>>>(agg, x, W1l, W1r, b1, out, N);

    // Layer 2: out = sage(h), h lives in d_out (in-place safe: each block
    // only reads its own rows and writes them after all its reads)
    agg_mean<<<aggblk, 256, 0, stream>>>(out, rowptr, csr, agg, N);
    sage_gemm<false><<<gemmblk, 256, 0, stream>>>(agg, out, W2l, W2r, b2, out, N);
}

// Round 2
// 328.308 us; speedup vs baseline: 1.6336x; 1.6336x over previous
//
#include <hip/hip_runtime.h>
#include <hip/hip_bf16.h>

// GraphSAGE 2-layer, bf16-MFMA version.
// sage(feat) = mean_agg(feat) @ Wl^T + feat @ Wr^T + b
// Treated as [N,256]@[256,128] with K = agg(128) || feat(128), bf16 inputs,
// f32 accumulate via v_mfma_f32_16x16x32_bf16.

#define D 128
#define SCAN_BLK 1024

typedef __attribute__((ext_vector_type(8))) short bf16x8;
typedef __attribute__((ext_vector_type(4))) float f32x4;

__device__ inline ushort f2bf(float f) {
    uint u = __float_as_uint(f);
    u += 0x7FFF + ((u >> 16) & 1);            // round-to-nearest-even
    return (ushort)(u >> 16);
}
__device__ inline float bf2f(ushort h) { return __uint_as_float(((uint)h) << 16); }

// ---------------- CSR construction ----------------

__global__ void count_deg(const int* __restrict__ ei, int* __restrict__ deg, int E) {
    int e = blockIdx.x * 256 + threadIdx.x;
    if (e < E) atomicAdd(&deg[ei[E + e]], 1);   // dst row
}

__global__ __launch_bounds__(SCAN_BLK) void scan_local(
        const int* __restrict__ deg, int* __restrict__ rowptr,
        int* __restrict__ partials, int n) {
    __shared__ int sdata[SCAN_BLK];
    int tid = threadIdx.x;
    int i = blockIdx.x * SCAN_BLK + tid;
    int v = (i < n) ? deg[i] : 0;
    sdata[tid] = v;
    __syncthreads();
    #pragma unroll
    for (int off = 1; off < SCAN_BLK; off <<= 1) {
        int t = (tid >= off) ? sdata[tid - off] : 0;
        __syncthreads();
        sdata[tid] += t;
        __syncthreads();
    }
    if (i < n) rowptr[i] = sdata[tid] - v;              // local exclusive
    if (tid == SCAN_BLK - 1) partials[blockIdx.x] = sdata[SCAN_BLK - 1];
}

__global__ __launch_bounds__(SCAN_BLK) void scan_partials(
        const int* __restrict__ partials, int* __restrict__ bases,
        int* __restrict__ rowptr, int nblocks, int n) {
    __shared__ int sdata[SCAN_BLK];
    int tid = threadIdx.x;
    int v = (tid < nblocks) ? partials[tid] : 0;
    sdata[tid] = v;
    __syncthreads();
    #pragma unroll
    for (int off = 1; off < SCAN_BLK; off <<= 1) {
        int t = (tid >= off) ? sdata[tid - off] : 0;
        __syncthreads();
        sdata[tid] += t;
        __syncthreads();
    }
    if (tid < nblocks) bases[tid] = sdata[tid] - v;
    if (tid == SCAN_BLK - 1) rowptr[n] = sdata[SCAN_BLK - 1];  // total = E
}

__global__ void add_bases(int* __restrict__ rowptr, const int* __restrict__ bases, int n) {
    int i = blockIdx.x * 256 + threadIdx.x;
    if (i < n) rowptr[i] += bases[i >> 10];
}

__global__ void fill_csr(const int* __restrict__ ei, int* __restrict__ cursor,
                         const int* __restrict__ rowptr, int* __restrict__ csr, int E) {
    int e = blockIdx.x * 256 + threadIdx.x;
    if (e < E) {
        int s = ei[e];          // src
        int d = ei[E + e];      // dst
        int pos = atomicAdd(&cursor[d], 1);
        csr[rowptr[d] + pos] = s;
    }
}

// ---------------- f32 -> bf16 bulk convert (8 elems/thread) ----------------

__global__ __launch_bounds__(256) void to_bf16(const float* __restrict__ in,
                                               ushort* __restrict__ out, int n8) {
    int i = blockIdx.x * 256 + threadIdx.x;
    if (i >= n8) return;
    const float4* p = (const float4*)in;
    float4 a = p[i * 2], b = p[i * 2 + 1];
    uint4 pk;
    pk.x = (uint)f2bf(a.x) | ((uint)f2bf(a.y) << 16);
    pk.y = (uint)f2bf(a.z) | ((uint)f2bf(a.w) << 16);
    pk.z = (uint)f2bf(b.x) | ((uint)f2bf(b.y) << 16);
    pk.w = (uint)f2bf(b.z) | ((uint)f2bf(b.w) << 16);
    *(uint4*)&out[i * 8] = pk;
}

// ---------------- pack Wl||Wr (f32) into bf16 Wcat[128][256] ----------------

__global__ __launch_bounds__(256) void prep_w(const float* __restrict__ Wl,
                                              const float* __restrict__ Wr,
                                              ushort* __restrict__ wcat) {
    int t = blockIdx.x * 256 + threadIdx.x;   // 8192 threads, 4 elems each
    int e = t * 4;
    int row = e >> 8;          // output feature n
    int k = e & 255;
    const float* src = (k < 128) ? &Wl[row * 128 + k] : &Wr[row * 128 + k - 128];
    float4 v = *(const float4*)src;
    uint2 pk;
    pk.x = (uint)f2bf(v.x) | ((uint)f2bf(v.y) << 16);
    pk.y = (uint)f2bf(v.z) | ((uint)f2bf(v.w) << 16);
    *(uint2*)&wcat[e] = pk;
}

// ---------------- mean aggregation: half-wave (32 lanes) per node ----------------

__global__ __launch_bounds__(256) void agg_mean_b(
        const ushort* __restrict__ feat, const int* __restrict__ rowptr,
        const int* __restrict__ csr, ushort* __restrict__ aggout, int n) {
    int node = (blockIdx.x * 256 + threadIdx.x) >> 5;
    int lane = threadIdx.x & 31;
    if (node >= n) return;
    int beg = rowptr[node], end = rowptr[node + 1];
    float a0 = 0.f, a1 = 0.f, a2 = 0.f, a3 = 0.f;
    for (int e = beg; e < end; ++e) {
        int s = csr[e];
        uint2 v = *(const uint2*)&feat[s * D + lane * 4];
        a0 += __uint_as_float(v.x << 16);
        a1 += __uint_as_float(v.x & 0xFFFF0000u);
        a2 += __uint_as_float(v.y << 16);
        a3 += __uint_as_float(v.y & 0xFFFF0000u);
    }
    float inv = (end > beg) ? 1.0f / (float)(end - beg) : 0.0f;
    uint2 pk;
    pk.x = (uint)f2bf(a0 * inv) | ((uint)f2bf(a1 * inv) << 16);
    pk.y = (uint)f2bf(a2 * inv) | ((uint)f2bf(a3 * inv) << 16);
    *(uint2*)&aggout[node * D + lane * 4] = pk;
}

// ---------------- MFMA dual GEMM ----------------
// Block: 256 thr (4 waves), 128 rows. Wave w: rows w*32..w*32+31 (2 row-tiles
// of 16) x all 128 cols (8 col-tiles). K-loop kc=0..7: kc<4 reads agg, else feat.
// Wcat staged in 64KB LDS, XOR-swizzled (row stride 512B would be 16-way
// bank conflict on ds_read_b128; byte ^= (row&7)<<4 spreads it -> ~2-way, free).

template <bool OUT_BF16, bool RELU>
__global__ __launch_bounds__(256) void sage_gemm_mfma(
        const ushort* __restrict__ aggb, const ushort* __restrict__ featb,
        const ushort* __restrict__ wcat, const float* __restrict__ bias,
        void* __restrict__ outp, int n) {
    __shared__ char lds[65536];        // Wcat[128][256] bf16, swizzled
    int tid = threadIdx.x;

    #pragma unroll
    for (int i = 0; i < 16; ++i) {
        int e = (tid + i * 256) * 8;            // element index (8 bf16 / iter)
        int byte = e * 2;
        int row = byte >> 9;                    // 512 B per row
        int sb = byte ^ ((row & 7) << 4);
        *(uint4*)&lds[sb] = *(const uint4*)&wcat[e];
    }
    __syncthreads();

    int wave = tid >> 6, l = tid & 63;
    int l15 = l & 15, lhi = l >> 4;
    int row_base = blockIdx.x * 128 + wave * 32;

    f32x4 zero = {0.f, 0.f, 0.f, 0.f};
    f32x4 acc[2][8];
    #pragma unroll
    for (int t = 0; t < 2; ++t)
        #pragma unroll
        for (int j = 0; j < 8; ++j) acc[t][j] = zero;

    int ra0 = row_base + l15;       if (ra0 > n - 1) ra0 = n - 1;
    int ra1 = row_base + 16 + l15;  if (ra1 > n - 1) ra1 = n - 1;

    for (int kc = 0; kc < 8; ++kc) {
        const ushort* asrc = (kc < 4) ? aggb : featb;
        int klocal = (kc & 3) * 32 + lhi * 8;
        bf16x8 a0 = *(const bf16x8*)&asrc[ra0 * D + klocal];
        bf16x8 a1 = *(const bf16x8*)&asrc[ra1 * D + klocal];
        bf16x8 b[8];
        #pragma unroll
        for (int j = 0; j < 8; ++j) {
            int brow = l15 + j * 16;
            int bbyte = (brow << 9) + kc * 64 + lhi * 16;
            b[j] = *(const bf16x8*)&lds[bbyte ^ ((brow & 7) << 4)];
        }
        #pragma unroll
        for (int j = 0; j < 8; ++j) {
            acc[0][j] = __builtin_amdgcn_mfma_f32_16x16x32_bf16(a0, b[j], acc[0][j], 0, 0, 0);
            acc[1][j] = __builtin_amdgcn_mfma_f32_16x16x32_bf16(a1, b[j], acc[1][j], 0, 0, 0);
        }
    }

    // epilogue: C/D layout col = lane&15, row = (lane>>4)*4 + reg
    #pragma unroll
    for (int t = 0; t < 2; ++t) {
        #pragma unroll
        for (int j = 0; j < 8; ++j) {
            int col = j * 16 + l15;
            float bv = bias[col];
            #pragma unroll
            for (int r = 0; r < 4; ++r) {
                int grow = row_base + t * 16 + lhi * 4 + r;
                if (grow >= n) continue;
                float v = acc[t][j][r] + bv;
                if (RELU) v = fmaxf(v, 0.f);
                if (OUT_BF16) ((ushort*)outp)[grow * D + col] = f2bf(v);
                else          ((float*)outp)[grow * D + col] = v;
            }
        }
    }
}

// ---------------- launch ----------------

extern "C" void kernel_launch(void* const* d_in, const int* in_sizes, int n_in,
                              void* d_out, int out_size, void* d_ws, size_t ws_size,
                              hipStream_t stream) {
    const float* x   = (const float*)d_in[0];
    const int*   ei  = (const int*)d_in[1];
    const float* W1l = (const float*)d_in[2];
    const float* b1  = (const float*)d_in[3];
    const float* W1r = (const float*)d_in[4];
    const float* W2l = (const float*)d_in[5];
    const float* b2  = (const float*)d_in[6];
    const float* W2r = (const float*)d_in[7];
    float* out = (float*)d_out;

    const int N = in_sizes[0] / D;
    const int E = in_sizes[1] / 2;

    // workspace layout (bf16 feature buffers)
    ushort* aggb  = (ushort*)d_ws;                        // N*D bf16
    ushort* hb    = aggb + (size_t)N * D;                 // N*D bf16 (xb, then h)
    ushort* wcat  = hb + (size_t)N * D;                   // 128*256 bf16
    int* deg      = (int*)(wcat + 128 * 256);             // N (reused as cursor)
    int* rowptr   = deg + N;                              // N+1
    int* csr      = rowptr + N + 1;                       // E
    int* parts    = csr + E;                              // 1024
    int* bases    = parts + SCAN_BLK;                     // 1024

    const int nchunks = (N + SCAN_BLK - 1) / SCAN_BLK;
    const int eblk = (E + 255) / 256;
    const int nblk = (N + 255) / 256;
    const int n8 = N * D / 8;

    // ---- CSR build (dst -> list of src) ----
    hipMemsetAsync(deg, 0, (size_t)N * sizeof(int), stream);
    count_deg<<<eblk, 256, 0, stream>>>(ei, deg, E);
    scan_local<<<nchunks, SCAN_BLK, 0, stream>>>(deg, rowptr, parts, N);
    scan_partials<<<1, SCAN_BLK, 0, stream>>>(parts, bases, rowptr, nchunks, N);
    add_bases<<<nblk, 256, 0, stream>>>(rowptr, bases, N);
    hipMemsetAsync(deg, 0, (size_t)N * sizeof(int), stream);   // deg -> cursor
    fill_csr<<<eblk, 256, 0, stream>>>(ei, deg, rowptr, csr, E);

    // ---- x -> bf16 ----
    to_bf16<<<(n8 + 255) / 256, 256, 0, stream>>>(x, hb, n8);

    const int aggblk = (N * 32 + 255) / 256;      // half-wave per node
    const int gemmblk = (N + 127) / 128;

    // ---- Layer 1: h = relu(sage(x)), h stored bf16 in-place over xb ----
    prep_w<<<32, 256, 0, stream>>>(W1l, W1r, wcat);
    agg_mean_b<<<aggblk, 256, 0, stream>>>(hb, rowptr, csr, aggb, N);
    sage_gemm_mfma<true, true><<<gemmblk, 256, 0, stream>>>(aggb, hb, wcat, b1, hb, N);

    // ---- Layer 2: out = sage(h) -> f32 d_out ----
    prep_w<<<32, 256, 0, stream>>>(W2l, W2r, wcat);
    agg_mean_b<<<aggblk, 256, 0, stream>>>(hb, rowptr, csr, aggb, N);
    sage_gemm_mfma<false, false><<<gemmblk, 256, 0, stream>>>(aggb, hb, wcat, b2, out, N);
}

// Round 3
// 290.518 us; speedup vs baseline: 1.8461x; 1.1301x over previous
//
#include <hip/hip_runtime.h>
#include <hip/hip_bf16.h>

// GraphSAGE 2-layer, bf16-MFMA version.
// sage(feat) = mean_agg(feat) @ Wl^T + feat @ Wr^T + b
// Treated as [N,256]@[256,128] with K = agg(128) || feat(128), bf16 inputs,
// f32 accumulate via v_mfma_f32_16x16x32_bf16.

#define D 128
#define SCAN_BLK 1024

typedef __attribute__((ext_vector_type(8))) short bf16x8;
typedef __attribute__((ext_vector_type(4))) float f32x4;

__device__ inline ushort f2bf(float f) {
    uint u = __float_as_uint(f);
    u += 0x7FFF + ((u >> 16) & 1);            // round-to-nearest-even
    return (ushort)(u >> 16);
}

// ---------------- CSR construction ----------------

__global__ void count_deg(const int* __restrict__ ei, int* __restrict__ deg, int E) {
    int e = blockIdx.x * 256 + threadIdx.x;
    if (e < E) atomicAdd(&deg[ei[E + e]], 1);   // dst row
}

__global__ __launch_bounds__(SCAN_BLK) void scan_local(
        const int* __restrict__ deg, int* __restrict__ rowptr,
        int* __restrict__ partials, int n) {
    __shared__ int sdata[SCAN_BLK];
    int tid = threadIdx.x;
    int i = blockIdx.x * SCAN_BLK + tid;
    int v = (i < n) ? deg[i] : 0;
    sdata[tid] = v;
    __syncthreads();
    #pragma unroll
    for (int off = 1; off < SCAN_BLK; off <<= 1) {
        int t = (tid >= off) ? sdata[tid - off] : 0;
        __syncthreads();
        sdata[tid] += t;
        __syncthreads();
    }
    if (i < n) rowptr[i] = sdata[tid] - v;              // local exclusive
    if (tid == SCAN_BLK - 1) partials[blockIdx.x] = sdata[SCAN_BLK - 1];
}

__global__ __launch_bounds__(SCAN_BLK) void scan_partials(
        const int* __restrict__ partials, int* __restrict__ bases,
        int* __restrict__ rowptr, int nblocks, int n) {
    __shared__ int sdata[SCAN_BLK];
    int tid = threadIdx.x;
    int v = (tid < nblocks) ? partials[tid] : 0;
    sdata[tid] = v;
    __syncthreads();
    #pragma unroll
    for (int off = 1; off < SCAN_BLK; off <<= 1) {
        int t = (tid >= off) ? sdata[tid - off] : 0;
        __syncthreads();
        sdata[tid] += t;
        __syncthreads();
    }
    if (tid < nblocks) bases[tid] = sdata[tid] - v;
    if (tid == SCAN_BLK - 1) rowptr[n] = sdata[SCAN_BLK - 1];  // total = E
}

__global__ void add_bases(int* __restrict__ rowptr, const int* __restrict__ bases, int n) {
    int i = blockIdx.x * 256 + threadIdx.x;
    if (i < n) rowptr[i] += bases[i >> 10];
}

__global__ void fill_csr(const int* __restrict__ ei, int* __restrict__ cursor,
                         const int* __restrict__ rowptr, int* __restrict__ csr, int E) {
    int e = blockIdx.x * 256 + threadIdx.x;
    if (e < E) {
        int s = ei[e];          // src
        int d = ei[E + e];      // dst
        int pos = atomicAdd(&cursor[d], 1);
        csr[rowptr[d] + pos] = s;
    }
}

// ---------------- f32 -> bf16 bulk convert (8 elems/thread) ----------------

__global__ __launch_bounds__(256) void to_bf16(const float* __restrict__ in,
                                               ushort* __restrict__ out, int n8) {
    int i = blockIdx.x * 256 + threadIdx.x;
    if (i >= n8) return;
    const float4* p = (const float4*)in;
    float4 a = p[i * 2], b = p[i * 2 + 1];
    uint4 pk;
    pk.x = (uint)f2bf(a.x) | ((uint)f2bf(a.y) << 16);
    pk.y = (uint)f2bf(a.z) | ((uint)f2bf(a.w) << 16);
    pk.z = (uint)f2bf(b.x) | ((uint)f2bf(b.y) << 16);
    pk.w = (uint)f2bf(b.z) | ((uint)f2bf(b.w) << 16);
    *(uint4*)&out[i * 8] = pk;
}

// ---------------- pack Wl||Wr (f32) into bf16 Wcat[128][256] ----------------

__global__ __launch_bounds__(256) void prep_w(const float* __restrict__ Wl,
                                              const float* __restrict__ Wr,
                                              ushort* __restrict__ wcat) {
    int t = blockIdx.x * 256 + threadIdx.x;   // 8192 threads, 4 elems each
    int e = t * 4;
    int row = e >> 8;          // output feature n
    int k = e & 255;
    const float* src = (k < 128) ? &Wl[row * 128 + k] : &Wr[row * 128 + k - 128];
    float4 v = *(const float4*)src;
    uint2 pk;
    pk.x = (uint)f2bf(v.x) | ((uint)f2bf(v.y) << 16);
    pk.y = (uint)f2bf(v.z) | ((uint)f2bf(v.w) << 16);
    *(uint2*)&wcat[e] = pk;
}

// ---------------- mean aggregation: half-wave per node, 8 gathers in flight --------

__global__ __launch_bounds__(256) void agg_mean_b(
        const ushort* __restrict__ feat, const int* __restrict__ rowptr,
        const int* __restrict__ csr, ushort* __restrict__ aggout, int n) {
    int node = (blockIdx.x * 256 + threadIdx.x) >> 5;
    int lane = threadIdx.x & 31;
    if (node >= n) return;
    int beg = rowptr[node], end = rowptr[node + 1];
    float a0 = 0.f, a1 = 0.f, a2 = 0.f, a3 = 0.f;
    for (int e = beg; e < end; e += 8) {
        uint2 v[8];
        float w[8];
        #pragma unroll
        for (int u = 0; u < 8; ++u) {
            int idx = e + u;
            int safe = (idx < end) ? idx : beg;       // duplicate row, weight 0
            int s = csr[safe];
            v[u] = *(const uint2*)&feat[s * D + lane * 4];
            w[u] = (idx < end) ? 1.f : 0.f;
        }
        #pragma unroll
        for (int u = 0; u < 8; ++u) {
            a0 = fmaf(w[u], __uint_as_float(v[u].x << 16), a0);
            a1 = fmaf(w[u], __uint_as_float(v[u].x & 0xFFFF0000u), a1);
            a2 = fmaf(w[u], __uint_as_float(v[u].y << 16), a2);
            a3 = fmaf(w[u], __uint_as_float(v[u].y & 0xFFFF0000u), a3);
        }
    }
    float inv = (end > beg) ? 1.0f / (float)(end - beg) : 0.0f;
    uint2 pk;
    pk.x = (uint)f2bf(a0 * inv) | ((uint)f2bf(a1 * inv) << 16);
    pk.y = (uint)f2bf(a2 * inv) | ((uint)f2bf(a3 * inv) << 16);
    *(uint2*)&aggout[node * D + lane * 4] = pk;
}

// ---------------- MFMA dual GEMM, two-stage 32KB LDS ----------------
// Block: 256 thr (4 waves), 128 rows. Wave w: rows w*32..+31 (2 row-tiles of 16)
// x 128 cols (8 col-tiles). Stage Wl-half (32KB, swizzled), compute kc 0-3 from
// agg; restage Wr-half, compute from feat. Row stride 256B would be 16-way bank
// conflict on ds_read_b128; byte ^= (row&7)<<4 -> 2-way (free, m136).

template <bool OUT_BF16, bool RELU>
__global__ __launch_bounds__(256) void sage_gemm_mfma(
        const ushort* __restrict__ aggb, const ushort* __restrict__ featb,
        const ushort* __restrict__ wcat, const float* __restrict__ bias,
        void* __restrict__ outp, int n) {
    __shared__ char lds[32768];        // one W-half [128 rows][128 k] bf16, swizzled
    int tid = threadIdx.x;
    int wave = tid >> 6, l = tid & 63;
    int l15 = l & 15, lhi = l >> 4;
    int row_base = blockIdx.x * 128 + wave * 32;

    f32x4 zero = {0.f, 0.f, 0.f, 0.f};
    f32x4 acc[2][8];
    #pragma unroll
    for (int t = 0; t < 2; ++t)
        #pragma unroll
        for (int j = 0; j < 8; ++j) acc[t][j] = zero;

    int ra0 = row_base + l15;       if (ra0 > n - 1) ra0 = n - 1;
    int ra1 = row_base + 16 + l15;  if (ra1 > n - 1) ra1 = n - 1;

    #pragma unroll
    for (int half = 0; half < 2; ++half) {
        if (half) __syncthreads();     // all reads of previous half done
        // stage 32KB: 2048 x uint4, 8 per thread
        #pragma unroll
        for (int rep = 0; rep < 8; ++rep) {
            int chunk = tid + rep * 256;          // 0..2047
            int r = chunk >> 4;                   // 16 chunks (256B) per row
            int c = chunk & 15;                   // 16B chunk within row
            int byte = (r << 8) + (c << 4);
            int sb = byte ^ ((r & 7) << 4);
            *(uint4*)&lds[sb] = *(const uint4*)&wcat[r * 256 + half * 128 + c * 8];
        }
        __syncthreads();

        const ushort* asrc = half ? featb : aggb;
        #pragma unroll
        for (int kc = 0; kc < 4; ++kc) {
            int klocal = kc * 32 + lhi * 8;
            bf16x8 a0 = *(const bf16x8*)&asrc[ra0 * D + klocal];
            bf16x8 a1 = *(const bf16x8*)&asrc[ra1 * D + klocal];
            #pragma unroll
            for (int j = 0; j < 8; ++j) {
                int brow = l15 + j * 16;
                int bbyte = (brow << 8) + kc * 64 + lhi * 16;
                bf16x8 b = *(const bf16x8*)&lds[bbyte ^ ((brow & 7) << 4)];
                acc[0][j] = __builtin_amdgcn_mfma_f32_16x16x32_bf16(a0, b, acc[0][j], 0, 0, 0);
                acc[1][j] = __builtin_amdgcn_mfma_f32_16x16x32_bf16(a1, b, acc[1][j], 0, 0, 0);
            }
        }
    }

    // epilogue: C/D layout col = lane&15, row = (lane>>4)*4 + reg
    #pragma unroll
    for (int t = 0; t < 2; ++t) {
        #pragma unroll
        for (int j = 0; j < 8; ++j) {
            int col = j * 16 + l15;
            float bv = bias[col];
            #pragma unroll
            for (int r = 0; r < 4; ++r) {
                int grow = row_base + t * 16 + lhi * 4 + r;
                if (grow >= n) continue;
                float v = acc[t][j][r] + bv;
                if (RELU) v = fmaxf(v, 0.f);
                if (OUT_BF16) ((ushort*)outp)[grow * D + col] = f2bf(v);
                else          ((float*)outp)[grow * D + col] = v;
            }
        }
    }
}

// ---------------- launch ----------------

extern "C" void kernel_launch(void* const* d_in, const int* in_sizes, int n_in,
                              void* d_out, int out_size, void* d_ws, size_t ws_size,
                              hipStream_t stream) {
    const float* x   = (const float*)d_in[0];
    const int*   ei  = (const int*)d_in[1];
    const float* W1l = (const float*)d_in[2];
    const float* b1  = (const float*)d_in[3];
    const float* W1r = (const float*)d_in[4];
    const float* W2l = (const float*)d_in[5];
    const float* b2  = (const float*)d_in[6];
    const float* W2r = (const float*)d_in[7];
    float* out = (float*)d_out;

    const int N = in_sizes[0] / D;
    const int E = in_sizes[1] / 2;

    // workspace layout (bf16 feature buffers)
    ushort* aggb  = (ushort*)d_ws;                        // N*D bf16
    ushort* hb    = aggb + (size_t)N * D;                 // N*D bf16 (xb, then h)
    ushort* wcat  = hb + (size_t)N * D;                   // 128*256 bf16
    int* deg      = (int*)(wcat + 128 * 256);             // N (reused as cursor)
    int* rowptr   = deg + N;                              // N+1
    int* csr      = rowptr + N + 1;                       // E
    int* parts    = csr + E;                              // 1024
    int* bases    = parts + SCAN_BLK;                     // 1024

    const int nchunks = (N + SCAN_BLK - 1) / SCAN_BLK;
    const int eblk = (E + 255) / 256;
    const int nblk = (N + 255) / 256;
    const int n8 = N * D / 8;

    // ---- CSR build (dst -> list of src) ----
    hipMemsetAsync(deg, 0, (size_t)N * sizeof(int), stream);
    count_deg<<<eblk, 256, 0, stream>>>(ei, deg, E);
    scan_local<<<nchunks, SCAN_BLK, 0, stream>>>(deg, rowptr, parts, N);
    scan_partials<<<1, SCAN_BLK, 0, stream>>>(parts, bases, rowptr, nchunks, N);
    add_bases<<<nblk, 256, 0, stream>>>(rowptr, bases, N);
    hipMemsetAsync(deg, 0, (size_t)N * sizeof(int), stream);   // deg -> cursor
    fill_csr<<<eblk, 256, 0, stream>>>(ei, deg, rowptr, csr, E);

    // ---- x -> bf16 ----
    to_bf16<<<(n8 + 255) / 256, 256, 0, stream>>>(x, hb, n8);

    const int aggblk = (N * 32 + 255) / 256;      // half-wave per node
    const int gemmblk = (N + 127) / 128;

    // ---- Layer 1: h = relu(sage(x)), h stored bf16 in-place over xb ----
    prep_w<<<32, 256, 0, stream>>>(W1l, W1r, wcat);
    agg_mean_b<<<aggblk, 256, 0, stream>>>(hb, rowptr, csr, aggb, N);
    sage_gemm_mfma<true, true><<<gemmblk, 256, 0, stream>>>(aggb, hb, wcat, b1, hb, N);

    // ---- Layer 2: out = sage(h) -> f32 d_out ----
    prep_w<<<32, 256, 0, stream>>>(W2l, W2r, wcat);
    agg_mean_b<<<aggblk, 256, 0, stream>>>(hb, rowptr, csr, aggb, N);
    sage_gemm_mfma<false, false><<<gemmblk, 256, 0, stream>>>(aggb, hb, wcat, b2, out, N);
}